// Round 1
// baseline (193.939 us; speedup 1.0000x reference)
//
#include <hip/hip_runtime.h>

#define N_RAYS 65536
#define N_PTS 128
#define FEAT 3
#define FAR_DELTA 1e10f

#define NBLOCKS 2048                 // 8 blocks/CU on 256 CUs: fully resident, no churn
#define RAYS_PER_ITER 8              // rays per block-iteration (one 32-lane segment each)
#define NITERS (N_RAYS / (NBLOCKS * RAYS_PER_ITER))   // 4

// 2 rays per wave: lane = 32*seg + sl; lane owns samples 4*sl .. 4*sl+3 of its ray.
// depth/density load as one float4 per lane (perfectly coalesced per segment).
// feature rows are staged block-cooperatively into LDS with linear float4 loads
// (ideal coalescing), then read per-lane at 48 B stride from LDS (cheap 4-way
// conflict instead of 3x strided global traffic).
__global__ __launch_bounds__(256, 8) void volrend_kernel(
    const float* __restrict__ depth,
    const float* __restrict__ density,
    const float* __restrict__ feature,
    float* __restrict__ out)
{
    __shared__ float4 sfeat[RAYS_PER_ITER * (N_PTS * FEAT / 4)];  // 8*96 f4 = 12 KB

    const int tid  = threadIdx.x;
    const int sl   = tid & 31;          // lane within 32-lane ray segment
    const int rloc = tid >> 5;          // ray within block (0..7)

    for (int it = 0; it < NITERS; ++it) {
        const int grp = (int)blockIdx.x + it * NBLOCKS;
        const int ray = grp * RAYS_PER_ITER + rloc;

        // ---- global loads (all coalesced float4) ----
        const float4 d   = *(const float4*)(depth   + ray * N_PTS + 4 * sl);
        const float4 rho = *(const float4*)(density + ray * N_PTS + 4 * sl);

        const float4* fsrc = (const float4*)feature
                           + (size_t)grp * (RAYS_PER_ITER * 96) + tid;
        float4 s0 = fsrc[0];
        float4 s1 = fsrc[256];
        float4 s2 = fsrc[512];

        if (it) __syncthreads();        // previous iteration's LDS reads complete
        sfeat[tid]       = s0;
        sfeat[tid + 256] = s1;
        sfeat[tid + 512] = s2;
        __syncthreads();

        // ---- taus + in-register local prefix (4 samples/lane) ----
        float nd = __shfl_down(d.x, 1);                 // next lane's first depth
        float t0 = rho.x * (d.y - d.x);
        float t1 = rho.y * (d.z - d.y);
        float t2 = rho.z * (d.w - d.z);
        float t3 = rho.w * ((sl == 31) ? FAR_DELTA : (nd - d.w));
        float p1 = t0, p2 = p1 + t1, p3 = p2 + t2, tot = p3 + t3;

        // ---- 32-lane segmented EXCLUSIVE scan of per-lane totals ----
        // shift-then-inclusive: the huge sentinel tau (sl==31) never enters any
        // lane's exclusive sum -> no catastrophic cancellation.
        float e = __shfl_up(tot, 1);
        if (sl == 0) e = 0.0f;
        #pragma unroll
        for (int off = 1; off < 32; off <<= 1) {
            float u = __shfl_up(e, off);
            if (sl >= off) e += u;      // guard masks cross-segment pulls
        }

        float T0 = __expf(-e);
        float T1 = __expf(-(e + p1));
        float T2 = __expf(-(e + p2));
        float T3 = __expf(-(e + p3));
        float T4 = __expf(-(e + tot)); // sl==31: exp(-1e10*rho) -> 0 (sentinel)
        float w0 = T0 - T1, w1 = T1 - T2, w2 = T2 - T3, w3 = T3 - T4;

        float acc3 = w0 * d.x + w1 * d.y + w2 * d.z + w3 * d.w;

        // lane's 4 samples' RGB = floats [12*sl, 12*sl+12) of the ray's row
        const float4* frow = &sfeat[rloc * 96 + sl * 3];
        float4 fa = frow[0], fb = frow[1], fc = frow[2];
        float acc0 = w0 * fa.x + w1 * fa.w + w2 * fb.z + w3 * fc.y;
        float acc1 = w0 * fa.y + w1 * fb.x + w2 * fb.w + w3 * fc.z;
        float acc2 = w0 * fa.z + w1 * fb.y + w2 * fc.x + w3 * fc.w;

        // ---- 32-lane segmented reduction (xor butterfly stays in segment) ----
        #pragma unroll
        for (int off = 16; off > 0; off >>= 1) {
            acc0 += __shfl_xor(acc0, off);
            acc1 += __shfl_xor(acc1, off);
            acc2 += __shfl_xor(acc2, off);
            acc3 += __shfl_xor(acc3, off);
        }
        if (sl == 0) {
            *(float4*)(out + ray * 4) = make_float4(acc0, acc1, acc2, acc3);
        }
    }
}

extern "C" void kernel_launch(void* const* d_in, const int* in_sizes, int n_in,
                              void* d_out, int out_size, void* d_ws, size_t ws_size,
                              hipStream_t stream) {
    const float* depth   = (const float*)d_in[0];
    const float* density = (const float*)d_in[1];
    const float* feature = (const float*)d_in[2];
    float* out = (float*)d_out;

    dim3 grid(NBLOCKS);
    dim3 block(256);
    volrend_kernel<<<grid, block, 0, stream>>>(depth, density, feature, out);
}